// Round 5
// baseline (51.414 us; speedup 1.0000x reference)
//
#include <hip/hip_runtime.h>
#include <hip/hip_bf16.h>

typedef __attribute__((ext_vector_type(8))) short  short8_t;
typedef __attribute__((ext_vector_type(4))) float  float4_t;
typedef __attribute__((ext_vector_type(4))) int    int4_t;
typedef __attribute__((ext_vector_type(2))) unsigned int uint2_t;

// f32 -> bf16 RNE (bit-twiddle; matches v_cvt rounding)
__device__ __forceinline__ unsigned short f2bf(float f) {
    unsigned int u = __builtin_bit_cast(unsigned int, f);
    u += 0x7FFFu + ((u >> 16) & 1u);
    return (unsigned short)(u >> 16);
}
__device__ __forceinline__ unsigned int cvtpk(float a, float b) {
    return (unsigned int)f2bf(a) | ((unsigned int)f2bf(b) << 16);
}
// gfx950 cross-lane row swaps (register-only; "+v" deps enforce ordering)
__device__ __forceinline__ void plane32_swap(unsigned int& a, unsigned int& b) {
    asm volatile("v_permlane32_swap_b32 %0, %1" : "+v"(a), "+v"(b));
}
__device__ __forceinline__ void plane16_swap(unsigned int& a, unsigned int& b) {
    asm volatile("v_permlane16_swap_b32 %0, %1" : "+v"(a), "+v"(b));
}

// ---- prepass: W2 -> granule-transposed bf16 W2s[ks][e] (16B granule = W2[e][8ks..8ks+8)),
//               W1 -> bf16 W1b. One kernel, 129 blocks.
__global__ void prep_kernel(const float* __restrict__ W2, const float* __restrict__ W1,
                            unsigned short* __restrict__ W2s, unsigned short* __restrict__ W1b) {
    const int bid = blockIdx.x, tid = threadIdx.x;
    if (bid < 128) {
        const int idx = bid * 256 + tid;          // 0..32767 granules
        const int e   = idx >> 7;                 // 0..255
        const int ks  = idx & 127;                // 0..127
        const float* src = W2 + (size_t)e * 1024 + ks * 8;   // coalesced 32B reads
        const float4_t v0 = *reinterpret_cast<const float4_t*>(src);
        const float4_t v1 = *reinterpret_cast<const float4_t*>(src + 4);
        int4_t p;
        p[0] = (int)cvtpk(v0[0], v0[1]);
        p[1] = (int)cvtpk(v0[2], v0[3]);
        p[2] = (int)cvtpk(v1[0], v1[1]);
        p[3] = (int)cvtpk(v1[2], v1[3]);
        *reinterpret_cast<int4_t*>(W2s + ((size_t)ks * 256 + e) * 8) = p;
    } else {
        const int base = tid * 32;                // 8192 floats total
        #pragma unroll
        for (int it = 0; it < 8; ++it) {
            const float4_t v = *reinterpret_cast<const float4_t*>(W1 + base + it * 4);
            uint2_t p;
            p[0] = cvtpk(v[0], v[1]);
            p[1] = cvtpk(v[2], v[3]);
            *reinterpret_cast<uint2_t*>(W1b + base + it * 4) = p;
        }
    }
}

// ---- fused, zero-LDS, zero-barrier kernel ----
// 2048 independent waves; wave = 64 rows x 64 cols output tile.
// q (registers) -> h via MFMA -> in-register permlane transpose -> A-frags
// W2 B-frags loaded straight from L2-resident granule-layout W2s.
template <bool WSOK>
__global__ __launch_bounds__(256, 2)
void ffq_kernel(const float* __restrict__ x,
                const float* __restrict__ theta,
                const float* __restrict__ W1f,
                const unsigned short* __restrict__ W1b,
                const float* __restrict__ W2f,
                const unsigned short* __restrict__ W2s,
                float* __restrict__ out)
{
    const int tid  = threadIdx.x;
    const int lane = tid & 63;
    const int w    = tid >> 6;
    const int bid  = blockIdx.x;
    const int ntile = bid & 3;                  // 4 col-tiles of 64 (shared by block's 4 waves -> L1 reuse on W2s)
    const int mtile = (bid >> 2) * 4 + w;       // 512 row-tiles of 64
    const int rowbase = mtile * 64;
    const int colbase = ntile * 64;
    const int lr = lane & 15;
    const int G  = lane >> 4;

    float th[8];
    #pragma unroll
    for (int j = 0; j < 8; ++j) th[j] = theta[j];

    // ---- q B-frags: lane<16 holds q[row=mt*16+lane][k=0..7], rest zero ----
    short8_t qf[4];
    #pragma unroll
    for (int mt = 0; mt < 4; ++mt) {
        short8_t v = {0, 0, 0, 0, 0, 0, 0, 0};
        if (lane < 16) {
            const float* xp = x + (size_t)(rowbase + mt * 16 + lane) * 256;
            const float4_t x0 = *reinterpret_cast<const float4_t*>(xp);
            const float4_t x1 = *reinterpret_cast<const float4_t*>(xp + 4);
            float qv[8];
            #pragma unroll
            for (int j = 0; j < 4; ++j) {
                qv[j]     = __cosf(x0[j]) * __cosf(th[j]);
                qv[4 + j] = __cosf(x1[j]) * __cosf(th[4 + j]);
            }
            int4_t pq;
            pq[0] = (int)cvtpk(qv[0], qv[1]);
            pq[1] = (int)cvtpk(qv[2], qv[3]);
            pq[2] = (int)cvtpk(qv[4], qv[5]);
            pq[3] = (int)cvtpk(qv[6], qv[7]);
            v = __builtin_bit_cast(short8_t, pq);
        }
        qf[mt] = v;
    }

    float4_t acc[4][4];
    #pragma unroll
    for (int i = 0; i < 4; ++i)
        #pragma unroll
        for (int j = 0; j < 4; ++j)
            acc[i][j] = (float4_t){0.f, 0.f, 0.f, 0.f};

    for (int kc = 0; kc < 1024; kc += 32) {
        // ---- W1 A-frags for the 2 f-tiles of this chunk (K=8 zero-padded) ----
        short8_t af0 = {0, 0, 0, 0, 0, 0, 0, 0};
        short8_t af1 = {0, 0, 0, 0, 0, 0, 0, 0};
        if (lane < 16) {
            if constexpr (WSOK) {
                af0 = *reinterpret_cast<const short8_t*>(W1b + (size_t)(kc + lane) * 8);
                af1 = *reinterpret_cast<const short8_t*>(W1b + (size_t)(kc + 16 + lane) * 8);
            } else {
                #pragma unroll
                for (int t = 0; t < 2; ++t) {
                    const float* src = W1f + (size_t)(kc + t * 16 + lane) * 8;
                    const float4_t v0 = *reinterpret_cast<const float4_t*>(src);
                    const float4_t v1 = *reinterpret_cast<const float4_t*>(src + 4);
                    int4_t p;
                    p[0] = (int)cvtpk(v0[0], v0[1]);
                    p[1] = (int)cvtpk(v0[2], v0[3]);
                    p[2] = (int)cvtpk(v1[0], v1[1]);
                    p[3] = (int)cvtpk(v1[2], v1[3]);
                    if (t == 0) af0 = __builtin_bit_cast(short8_t, p);
                    else        af1 = __builtin_bit_cast(short8_t, p);
                }
            }
        }

        // ---- W2 B-frags straight from global (L2): lane -> 16B granule (ks=kc/8+G, e) ----
        short8_t bf[4];
        #pragma unroll
        for (int cf = 0; cf < 4; ++cf) {
            const int e = colbase + cf * 16 + lr;
            if constexpr (WSOK) {
                bf[cf] = *reinterpret_cast<const short8_t*>(
                    W2s + (((size_t)(kc >> 3) + G) * 256 + e) * 8);
            } else {
                const float* p = W2f + (size_t)e * 1024 + kc + G * 8;
                const float4_t v0 = *reinterpret_cast<const float4_t*>(p);
                const float4_t v1 = *reinterpret_cast<const float4_t*>(p + 4);
                int4_t pb;
                pb[0] = (int)cvtpk(v0[0], v0[1]);
                pb[1] = (int)cvtpk(v0[2], v0[3]);
                pb[2] = (int)cvtpk(v1[0], v1[1]);
                pb[3] = (int)cvtpk(v1[2], v1[3]);
                bf[cf] = __builtin_bit_cast(short8_t, pb);
            }
        }

        // ---- h for own 64 rows x 32 f, relu, and in-register transpose to A-frags ----
        short8_t afrag[4];
        #pragma unroll
        for (int mt = 0; mt < 4; ++mt) {
            const float4_t t0 = __builtin_amdgcn_mfma_f32_16x16x32_bf16(
                af0, qf[mt], (float4_t){0.f, 0.f, 0.f, 0.f}, 0, 0, 0);
            const float4_t t1 = __builtin_amdgcn_mfma_f32_16x16x32_bf16(
                af1, qf[mt], (float4_t){0.f, 0.f, 0.f, 0.f}, 0, 0, 0);
            // lane holds m=lane&15; f = 16*ft + 4*G + r  (r = reg idx)
            unsigned int A_ = cvtpk(fmaxf(t0[0], 0.f), fmaxf(t0[1], 0.f)); // ft0, r0..1
            unsigned int B_ = cvtpk(fmaxf(t0[2], 0.f), fmaxf(t0[3], 0.f)); // ft0, r2..3
            unsigned int C_ = cvtpk(fmaxf(t1[0], 0.f), fmaxf(t1[1], 0.f)); // ft1, r0..1
            unsigned int D_ = cvtpk(fmaxf(t1[2], 0.f), fmaxf(t1[3], 0.f)); // ft1, r2..3
            // target A-frag vgpr v of lane (m=lane&15, G): f-pair (8G+2v, 8G+2v+1)
            // u0=(A@g0,A@g2,C@g0,C@g2), u1=(B@g0,B@g2,D@g0,D@g2),
            // u2=(A@g1,A@g3,C@g1,C@g3), u3=(B@g1,B@g3,D@g1,D@g3)
            plane32_swap(A_, C_);   // A_=(A0,A1,C0,C1)  C_=(A2,A3,C2,C3)
            plane16_swap(A_, C_);   // A_=u0             C_=u2
            plane32_swap(B_, D_);
            plane16_swap(B_, D_);   // B_=u1             D_=u3
            int4_t ua;
            ua[0] = (int)A_; ua[1] = (int)B_; ua[2] = (int)C_; ua[3] = (int)D_;
            afrag[mt] = __builtin_bit_cast(short8_t, ua);
        }

        // ---- main GEMM: 16 MFMA, fragment reuse 4x both sides ----
        #pragma unroll
        for (int mt = 0; mt < 4; ++mt)
            #pragma unroll
            for (int cf = 0; cf < 4; ++cf)
                acc[mt][cf] = __builtin_amdgcn_mfma_f32_16x16x32_bf16(
                    afrag[mt], bf[cf], acc[mt][cf], 0, 0, 0);
    }

    // ---- epilogue: C/D layout col=lane&15, row=(lane>>4)*4+reg ----
    #pragma unroll
    for (int mt = 0; mt < 4; ++mt)
        #pragma unroll
        for (int cf = 0; cf < 4; ++cf)
            #pragma unroll
            for (int r = 0; r < 4; ++r) {
                const int gr = rowbase + mt * 16 + G * 4 + r;
                const int gc = colbase + cf * 16 + lr;
                out[(size_t)gr * 256 + gc] = acc[mt][cf][r];
            }
}

extern "C" void kernel_launch(void* const* d_in, const int* in_sizes, int n_in,
                              void* d_out, int out_size, void* d_ws, size_t ws_size,
                              hipStream_t stream) {
    const float* x     = (const float*)d_in[0];   // [8,4096,256]
    const float* theta = (const float*)d_in[1];   // [8]
    const float* W1    = (const float*)d_in[2];   // [1024,8]
    const float* W2    = (const float*)d_in[3];   // [256,1024]
    float* out = (float*)d_out;                   // [8,4096,256] f32

    const size_t need = (size_t)(256 * 1024 + 8 * 1024) * sizeof(unsigned short);
    const bool wsok = (ws_size >= need);

    if (wsok) {
        unsigned short* W2s = (unsigned short*)d_ws;   // 512KB granule-transposed bf16
        unsigned short* W1b = W2s + 256 * 1024;        // 16KB bf16
        prep_kernel<<<129, 256, 0, stream>>>(W2, W1, W2s, W1b);
        ffq_kernel<true><<<512, 256, 0, stream>>>(x, theta, nullptr, W1b, nullptr, W2s, out);
    } else {
        ffq_kernel<false><<<512, 256, 0, stream>>>(x, theta, W1, nullptr, W2, nullptr, out);
    }
}

// Round 6
// 50.213 us; speedup vs baseline: 1.0239x; 1.0239x over previous
//
#include <hip/hip_runtime.h>
#include <hip/hip_bf16.h>

typedef __attribute__((ext_vector_type(8))) short  short8_t;
typedef __attribute__((ext_vector_type(4))) float  float4_t;
typedef __attribute__((ext_vector_type(4))) int    int4_t;
typedef __attribute__((ext_vector_type(2))) unsigned int uint2_t;

// f32 -> bf16 RNE (bit-twiddle; host-independent path, used only in prepass/fallback)
__device__ __forceinline__ unsigned short f2bf(float f) {
    unsigned int u = __builtin_bit_cast(unsigned int, f);
    u += 0x7FFFu + ((u >> 16) & 1u);
    return (unsigned short)(u >> 16);
}
__device__ __forceinline__ unsigned int cvtpk(float a, float b) {
    return (unsigned int)f2bf(a) | ((unsigned int)f2bf(b) << 16);
}
// HW packed convert: dst = {bf16(a), bf16(b)} in one VALU op (no builtin on gfx950)
__device__ __forceinline__ unsigned int cvtpk_hw(float a, float b) {
    unsigned int r;
    asm("v_cvt_pk_bf16_f32 %0, %1, %2" : "=v"(r) : "v"(a), "v"(b));
    return r;
}
// gfx950 cross-lane row swaps (pure dataflow; "+v" ties enforce ordering)
__device__ __forceinline__ void plane32_swap(unsigned int& a, unsigned int& b) {
    asm("v_permlane32_swap_b32 %0, %1" : "+v"(a), "+v"(b));
}
__device__ __forceinline__ void plane16_swap(unsigned int& a, unsigned int& b) {
    asm("v_permlane16_swap_b32 %0, %1" : "+v"(a), "+v"(b));
}

#define W1ROWS 1088   // 1024 real rows + 64 zero-pad rows (enables unconditional a-frag loads)

// ---- prepass: W2 -> granule-transposed bf16 W2s[ks][e]; W1 -> bf16 W1b (+zero pad) ----
__global__ void prep_kernel(const float* __restrict__ W2, const float* __restrict__ W1,
                            unsigned short* __restrict__ W2s, unsigned short* __restrict__ W1b) {
    const int bid = blockIdx.x, tid = threadIdx.x;
    if (bid < 128) {
        const int idx = bid * 256 + tid;          // 0..32767 granules
        const int e   = idx >> 7;                 // 0..255
        const int ks  = idx & 127;                // 0..127
        const float* src = W2 + (size_t)e * 1024 + ks * 8;   // coalesced 32B reads
        const float4_t v0 = *reinterpret_cast<const float4_t*>(src);
        const float4_t v1 = *reinterpret_cast<const float4_t*>(src + 4);
        int4_t p;
        p[0] = (int)cvtpk(v0[0], v0[1]);
        p[1] = (int)cvtpk(v0[2], v0[3]);
        p[2] = (int)cvtpk(v1[0], v1[1]);
        p[3] = (int)cvtpk(v1[2], v1[3]);
        *reinterpret_cast<int4_t*>(W2s + ((size_t)ks * 256 + e) * 8) = p;
    } else {
        const int base = tid * 32;                // 8192 floats total
        #pragma unroll
        for (int it = 0; it < 8; ++it) {
            const float4_t v = *reinterpret_cast<const float4_t*>(W1 + base + it * 4);
            uint2_t p;
            p[0] = cvtpk(v[0], v[1]);
            p[1] = cvtpk(v[2], v[3]);
            *reinterpret_cast<uint2_t*>(W1b + base + it * 4) = p;
        }
        // zero the 64 pad rows (512 shorts): 16 threads x 32 shorts
        if (tid < 16) {
            #pragma unroll
            for (int it = 0; it < 4; ++it) {
                int4_t z; z[0] = 0; z[1] = 0; z[2] = 0; z[3] = 0;
                *reinterpret_cast<int4_t*>(W1b + 8192 + tid * 32 + it * 8) = z;
            }
        }
    }
}

// ---- fused, zero-LDS, zero-barrier kernel ----
// 2048 independent waves; wave = 64 rows x 64 cols output tile.
// q (registers) -> h via MFMA -> in-register permlane transpose -> A-frags
// W2 B-frags loaded straight from L2-resident granule-layout W2s.
template <bool WSOK>
__global__ __launch_bounds__(256, 2)
void ffq_kernel(const float* __restrict__ x,
                const float* __restrict__ theta,
                const float* __restrict__ W1f,
                const unsigned short* __restrict__ W1b,
                const float* __restrict__ W2f,
                const unsigned short* __restrict__ W2s,
                float* __restrict__ out)
{
    const int tid  = threadIdx.x;
    const int lane = tid & 63;
    const int w    = tid >> 6;
    const int bid  = blockIdx.x;
    const int ntile = bid & 3;                  // 4 col-tiles of 64 (block's waves share W2s slice)
    const int mtile = (bid >> 2) * 4 + w;       // 512 row-tiles of 64
    const int rowbase = mtile * 64;
    const int colbase = ntile * 64;
    const int lr = lane & 15;
    const int G  = lane >> 4;

    float th[8];
    #pragma unroll
    for (int j = 0; j < 8; ++j) th[j] = theta[j];

    // ---- q B-frags: lane<16 holds q[row=mt*16+lane][k=0..7], rest MUST be zero ----
    short8_t qf[4];
    #pragma unroll
    for (int mt = 0; mt < 4; ++mt) {
        short8_t v = {0, 0, 0, 0, 0, 0, 0, 0};
        if (lane < 16) {
            const float* xp = x + (size_t)(rowbase + mt * 16 + lane) * 256;
            const float4_t x0 = *reinterpret_cast<const float4_t*>(xp);
            const float4_t x1 = *reinterpret_cast<const float4_t*>(xp + 4);
            float qv[8];
            #pragma unroll
            for (int j = 0; j < 4; ++j) {
                qv[j]     = __cosf(x0[j]) * __cosf(th[j]);
                qv[4 + j] = __cosf(x1[j]) * __cosf(th[4 + j]);
            }
            int4_t pq;
            pq[0] = (int)cvtpk(qv[0], qv[1]);
            pq[1] = (int)cvtpk(qv[2], qv[3]);
            pq[2] = (int)cvtpk(qv[4], qv[5]);
            pq[3] = (int)cvtpk(qv[6], qv[7]);
            v = __builtin_bit_cast(short8_t, pq);
        }
        qf[mt] = v;
    }

    float4_t acc[4][4];
    #pragma unroll
    for (int i = 0; i < 4; ++i)
        #pragma unroll
        for (int j = 0; j < 4; ++j)
            acc[i][j] = (float4_t){0.f, 0.f, 0.f, 0.f};

    #pragma unroll 2
    for (int kc = 0; kc < 1024; kc += 32) {
        // ---- W1 A-frags, UNCONDITIONAL (k-groups 1-3 garbage x zero-B = 0; pad keeps in-bounds/finite) ----
        short8_t af0, af1;
        if constexpr (WSOK) {
            af0 = *reinterpret_cast<const short8_t*>(W1b + (size_t)(kc + lane) * 8);
            af1 = *reinterpret_cast<const short8_t*>(W1b + (size_t)(kc + 16 + lane) * 8);
        } else {
            af0 = short8_t{0,0,0,0,0,0,0,0};
            af1 = short8_t{0,0,0,0,0,0,0,0};
            if (lane < 16) {
                #pragma unroll
                for (int t = 0; t < 2; ++t) {
                    const float* src = W1f + (size_t)(kc + t * 16 + lane) * 8;
                    const float4_t v0 = *reinterpret_cast<const float4_t*>(src);
                    const float4_t v1 = *reinterpret_cast<const float4_t*>(src + 4);
                    int4_t p;
                    p[0] = (int)cvtpk(v0[0], v0[1]);
                    p[1] = (int)cvtpk(v0[2], v0[3]);
                    p[2] = (int)cvtpk(v1[0], v1[1]);
                    p[3] = (int)cvtpk(v1[2], v1[3]);
                    if (t == 0) af0 = __builtin_bit_cast(short8_t, p);
                    else        af1 = __builtin_bit_cast(short8_t, p);
                }
            }
        }

        // ---- W2 B-frags straight from L2: lane -> 16B granule (ks=kc/8+G, e) ----
        short8_t bf[4];
        #pragma unroll
        for (int cf = 0; cf < 4; ++cf) {
            const int e = colbase + cf * 16 + lr;
            if constexpr (WSOK) {
                bf[cf] = *reinterpret_cast<const short8_t*>(
                    W2s + (((size_t)(kc >> 3) + G) * 256 + e) * 8);
            } else {
                const float* p = W2f + (size_t)e * 1024 + kc + G * 8;
                const float4_t v0 = *reinterpret_cast<const float4_t*>(p);
                const float4_t v1 = *reinterpret_cast<const float4_t*>(p + 4);
                int4_t pb;
                pb[0] = (int)cvtpk(v0[0], v0[1]);
                pb[1] = (int)cvtpk(v0[2], v0[3]);
                pb[2] = (int)cvtpk(v1[0], v1[1]);
                pb[3] = (int)cvtpk(v1[2], v1[3]);
                bf[cf] = __builtin_bit_cast(short8_t, pb);
            }
        }

        // ---- h for own 64 rows x 32 f, relu, in-register transpose to A-frags ----
        short8_t afrag[4];
        #pragma unroll
        for (int mt = 0; mt < 4; ++mt) {
            const float4_t t0 = __builtin_amdgcn_mfma_f32_16x16x32_bf16(
                af0, qf[mt], (float4_t){0.f, 0.f, 0.f, 0.f}, 0, 0, 0);
            const float4_t t1 = __builtin_amdgcn_mfma_f32_16x16x32_bf16(
                af1, qf[mt], (float4_t){0.f, 0.f, 0.f, 0.f}, 0, 0, 0);
            // lane holds m=lane&15; f = 16*ft + 4*G + r  (r = reg idx)
            unsigned int A_ = cvtpk_hw(fmaxf(t0[0], 0.f), fmaxf(t0[1], 0.f)); // ft0, r0..1
            unsigned int B_ = cvtpk_hw(fmaxf(t0[2], 0.f), fmaxf(t0[3], 0.f)); // ft0, r2..3
            unsigned int C_ = cvtpk_hw(fmaxf(t1[0], 0.f), fmaxf(t1[1], 0.f)); // ft1, r0..1
            unsigned int D_ = cvtpk_hw(fmaxf(t1[2], 0.f), fmaxf(t1[3], 0.f)); // ft1, r2..3
            // swap network -> A-frag vgpr v of lane (m, G): f-pair (8G+2v, 8G+2v+1)
            plane32_swap(A_, C_);
            plane16_swap(A_, C_);
            plane32_swap(B_, D_);
            plane16_swap(B_, D_);
            int4_t ua;
            ua[0] = (int)A_; ua[1] = (int)B_; ua[2] = (int)C_; ua[3] = (int)D_;
            afrag[mt] = __builtin_bit_cast(short8_t, ua);
        }

        // ---- main GEMM: 16 MFMA, fragment reuse 4x both sides ----
        #pragma unroll
        for (int mt = 0; mt < 4; ++mt)
            #pragma unroll
            for (int cf = 0; cf < 4; ++cf)
                acc[mt][cf] = __builtin_amdgcn_mfma_f32_16x16x32_bf16(
                    afrag[mt], bf[cf], acc[mt][cf], 0, 0, 0);
    }

    // ---- epilogue: C/D layout col=lane&15, row=(lane>>4)*4+reg ----
    #pragma unroll
    for (int mt = 0; mt < 4; ++mt)
        #pragma unroll
        for (int cf = 0; cf < 4; ++cf)
            #pragma unroll
            for (int r = 0; r < 4; ++r) {
                const int gr = rowbase + mt * 16 + G * 4 + r;
                const int gc = colbase + cf * 16 + lr;
                out[(size_t)gr * 256 + gc] = acc[mt][cf][r];
            }
}

extern "C" void kernel_launch(void* const* d_in, const int* in_sizes, int n_in,
                              void* d_out, int out_size, void* d_ws, size_t ws_size,
                              hipStream_t stream) {
    const float* x     = (const float*)d_in[0];   // [8,4096,256]
    const float* theta = (const float*)d_in[1];   // [8]
    const float* W1    = (const float*)d_in[2];   // [1024,8]
    const float* W2    = (const float*)d_in[3];   // [256,1024]
    float* out = (float*)d_out;                   // [8,4096,256] f32

    const size_t need = (size_t)(256 * 1024 + W1ROWS * 8) * sizeof(unsigned short);
    const bool wsok = (ws_size >= need);

    if (wsok) {
        unsigned short* W2s = (unsigned short*)d_ws;   // 512KB granule-transposed bf16
        unsigned short* W1b = W2s + 256 * 1024;        // 1088x8 bf16 (64 pad rows zeroed)
        prep_kernel<<<129, 256, 0, stream>>>(W2, W1, W2s, W1b);
        ffq_kernel<true><<<512, 256, 0, stream>>>(x, theta, nullptr, W1b, nullptr, W2s, out);
    } else {
        ffq_kernel<false><<<512, 256, 0, stream>>>(x, theta, W1, nullptr, W2, nullptr, out);
    }
}

// Round 7
// 48.838 us; speedup vs baseline: 1.0527x; 1.0282x over previous
//
#include <hip/hip_runtime.h>
#include <hip/hip_bf16.h>

typedef __attribute__((ext_vector_type(8))) short  short8_t;
typedef __attribute__((ext_vector_type(4))) float  float4_t;
typedef __attribute__((ext_vector_type(4))) int    int4_t;
typedef __attribute__((ext_vector_type(2))) unsigned int uint2_t;

// f32 -> bf16 RNE (bit-twiddle; prepass/fallback only)
__device__ __forceinline__ unsigned short f2bf(float f) {
    unsigned int u = __builtin_bit_cast(unsigned int, f);
    u += 0x7FFFu + ((u >> 16) & 1u);
    return (unsigned short)(u >> 16);
}
__device__ __forceinline__ unsigned int cvtpk(float a, float b) {
    return (unsigned int)f2bf(a) | ((unsigned int)f2bf(b) << 16);
}
// HW packed convert (no builtin on gfx950)
__device__ __forceinline__ unsigned int cvtpk_hw(float a, float b) {
    unsigned int r;
    asm("v_cvt_pk_bf16_f32 %0, %1, %2" : "=v"(r) : "v"(a), "v"(b));
    return r;
}
// gfx950 cross-lane row swaps (dataflow-ordered)
__device__ __forceinline__ void plane32_swap(unsigned int& a, unsigned int& b) {
    asm("v_permlane32_swap_b32 %0, %1" : "+v"(a), "+v"(b));
}
__device__ __forceinline__ void plane16_swap(unsigned int& a, unsigned int& b) {
    asm("v_permlane16_swap_b32 %0, %1" : "+v"(a), "+v"(b));
}

#define W1ROWS 1088   // 1024 + 64 zero-pad rows (unconditional a-frag loads)

// ---- prepass: W2 -> granule-transposed bf16 W2s[ks][e]; W1 -> bf16 W1b (+zero pad) ----
__global__ void prep_kernel(const float* __restrict__ W2, const float* __restrict__ W1,
                            unsigned short* __restrict__ W2s, unsigned short* __restrict__ W1b) {
    const int bid = blockIdx.x, tid = threadIdx.x;
    if (bid < 128) {
        const int idx = bid * 256 + tid;
        const int e   = idx >> 7;
        const int ks  = idx & 127;
        const float* src = W2 + (size_t)e * 1024 + ks * 8;
        const float4_t v0 = *reinterpret_cast<const float4_t*>(src);
        const float4_t v1 = *reinterpret_cast<const float4_t*>(src + 4);
        int4_t p;
        p[0] = (int)cvtpk(v0[0], v0[1]);
        p[1] = (int)cvtpk(v0[2], v0[3]);
        p[2] = (int)cvtpk(v1[0], v1[1]);
        p[3] = (int)cvtpk(v1[2], v1[3]);
        *reinterpret_cast<int4_t*>(W2s + ((size_t)ks * 256 + e) * 8) = p;
    } else {
        const int base = tid * 32;
        #pragma unroll
        for (int it = 0; it < 8; ++it) {
            const float4_t v = *reinterpret_cast<const float4_t*>(W1 + base + it * 4);
            uint2_t p;
            p[0] = cvtpk(v[0], v[1]);
            p[1] = cvtpk(v[2], v[3]);
            *reinterpret_cast<uint2_t*>(W1b + base + it * 4) = p;
        }
        if (tid < 16) {
            #pragma unroll
            for (int it = 0; it < 4; ++it) {
                int4_t z; z[0] = 0; z[1] = 0; z[2] = 0; z[3] = 0;
                *reinterpret_cast<int4_t*>(W1b + 8192 + tid * 32 + it * 8) = z;
            }
        }
    }
}

// ---- fused, zero-LDS, zero-barrier, 1-chunk-ahead prefetch ----
// 4096 independent waves; wave = 32 rows x 64 cols output tile (16 waves/CU).
// Block's 4 waves share one n-tile -> identical bf addresses -> L1 broadcast.
template <bool WSOK>
__global__ __launch_bounds__(256, 4)
void ffq_kernel(const float* __restrict__ x,
                const float* __restrict__ theta,
                const float* __restrict__ W1f,
                const unsigned short* __restrict__ W1b,
                const float* __restrict__ W2f,
                const unsigned short* __restrict__ W2s,
                float* __restrict__ out)
{
    const int tid  = threadIdx.x;
    const int lane = tid & 63;
    const int w    = tid >> 6;
    const int bid  = blockIdx.x;
    const int ntile = bid & 3;                  // 4 col-tiles of 64; shared across block's waves
    const int mtile = (bid >> 2) * 4 + w;       // 1024 row-tiles of 32
    const int rowbase = mtile * 32;
    const int colbase = ntile * 64;
    const int lr = lane & 15;
    const int G  = lane >> 4;

    // ---- q B-frags (2 m-tiles of 16 rows): lane<16 holds q[row][k=0..7], rest zero ----
    short8_t qf0 = {0,0,0,0,0,0,0,0}, qf1 = {0,0,0,0,0,0,0,0};
    if (lane < 16) {
        float th[8];
        #pragma unroll
        for (int j = 0; j < 8; ++j) th[j] = theta[j];
        #pragma unroll
        for (int mt = 0; mt < 2; ++mt) {
            const float* xp = x + (size_t)(rowbase + mt * 16 + lane) * 256;
            const float4_t x0 = *reinterpret_cast<const float4_t*>(xp);
            const float4_t x1 = *reinterpret_cast<const float4_t*>(xp + 4);
            float qv[8];
            #pragma unroll
            for (int j = 0; j < 4; ++j) {
                qv[j]     = __cosf(x0[j]) * __cosf(th[j]);
                qv[4 + j] = __cosf(x1[j]) * __cosf(th[4 + j]);
            }
            int4_t pq;
            pq[0] = (int)cvtpk(qv[0], qv[1]);
            pq[1] = (int)cvtpk(qv[2], qv[3]);
            pq[2] = (int)cvtpk(qv[4], qv[5]);
            pq[3] = (int)cvtpk(qv[6], qv[7]);
            if (mt == 0) qf0 = __builtin_bit_cast(short8_t, pq);
            else         qf1 = __builtin_bit_cast(short8_t, pq);
        }
    }

    // ---- load helpers ----
    auto ld_af = [&](int kc, int t) -> short8_t {
        if constexpr (WSOK) {
            return *reinterpret_cast<const short8_t*>(W1b + (size_t)(kc + t * 16 + lane) * 8);
        } else {
            short8_t r = {0,0,0,0,0,0,0,0};
            if (lane < 16) {
                const float* src = W1f + (size_t)(kc + t * 16 + lane) * 8;
                const float4_t v0 = *reinterpret_cast<const float4_t*>(src);
                const float4_t v1 = *reinterpret_cast<const float4_t*>(src + 4);
                int4_t p;
                p[0] = (int)cvtpk(v0[0], v0[1]);
                p[1] = (int)cvtpk(v0[2], v0[3]);
                p[2] = (int)cvtpk(v1[0], v1[1]);
                p[3] = (int)cvtpk(v1[2], v1[3]);
                r = __builtin_bit_cast(short8_t, p);
            }
            return r;
        }
    };
    auto ld_bf = [&](int kc, int cf) -> short8_t {
        const int e = colbase + cf * 16 + lr;
        if constexpr (WSOK) {
            return *reinterpret_cast<const short8_t*>(
                W2s + (((size_t)(kc >> 3) + G) * 256 + e) * 8);
        } else {
            const float* p = W2f + (size_t)e * 1024 + kc + G * 8;
            const float4_t v0 = *reinterpret_cast<const float4_t*>(p);
            const float4_t v1 = *reinterpret_cast<const float4_t*>(p + 4);
            int4_t pb;
            pb[0] = (int)cvtpk(v0[0], v0[1]);
            pb[1] = (int)cvtpk(v0[2], v0[3]);
            pb[2] = (int)cvtpk(v1[0], v1[1]);
            pb[3] = (int)cvtpk(v1[2], v1[3]);
            return __builtin_bit_cast(short8_t, pb);
        }
    };

    float4_t acc[2][4];
    #pragma unroll
    for (int i = 0; i < 2; ++i)
        #pragma unroll
        for (int j = 0; j < 4; ++j)
            acc[i][j] = (float4_t){0.f, 0.f, 0.f, 0.f};

    // ---- prologue: chunk-0 fragments ----
    short8_t af0_c = ld_af(0, 0), af1_c = ld_af(0, 1);
    short8_t bf0_c = ld_bf(0, 0), bf1_c = ld_bf(0, 1);
    short8_t bf2_c = ld_bf(0, 2), bf3_c = ld_bf(0, 3);

    #pragma unroll 2
    for (int kc = 0; kc < 1024; kc += 32) {
        // ---- prefetch chunk k+1 (wraps to 0 on last iter; harmless, cached) ----
        const int kn = (kc + 32) & 1023;
        short8_t af0_n = ld_af(kn, 0), af1_n = ld_af(kn, 1);
        short8_t bf0_n = ld_bf(kn, 0), bf1_n = ld_bf(kn, 1);
        short8_t bf2_n = ld_bf(kn, 2), bf3_n = ld_bf(kn, 3);

        // ---- h-phase for current chunk: 2 mt x 2 ft MFMA -> relu -> permlane transpose ----
        short8_t afrag0, afrag1;
        #pragma unroll
        for (int mt = 0; mt < 2; ++mt) {
            const short8_t qf = (mt == 0) ? qf0 : qf1;
            const float4_t t0 = __builtin_amdgcn_mfma_f32_16x16x32_bf16(
                af0_c, qf, (float4_t){0.f, 0.f, 0.f, 0.f}, 0, 0, 0);
            const float4_t t1 = __builtin_amdgcn_mfma_f32_16x16x32_bf16(
                af1_c, qf, (float4_t){0.f, 0.f, 0.f, 0.f}, 0, 0, 0);
            unsigned int A_ = cvtpk_hw(fmaxf(t0[0], 0.f), fmaxf(t0[1], 0.f));
            unsigned int B_ = cvtpk_hw(fmaxf(t0[2], 0.f), fmaxf(t0[3], 0.f));
            unsigned int C_ = cvtpk_hw(fmaxf(t1[0], 0.f), fmaxf(t1[1], 0.f));
            unsigned int D_ = cvtpk_hw(fmaxf(t1[2], 0.f), fmaxf(t1[3], 0.f));
            plane32_swap(A_, C_);
            plane16_swap(A_, C_);
            plane32_swap(B_, D_);
            plane16_swap(B_, D_);
            int4_t ua;
            ua[0] = (int)A_; ua[1] = (int)B_; ua[2] = (int)C_; ua[3] = (int)D_;
            if (mt == 0) afrag0 = __builtin_bit_cast(short8_t, ua);
            else         afrag1 = __builtin_bit_cast(short8_t, ua);
        }

        // ---- main GEMM: 8 MFMA (2 mt x 4 cf) ----
        acc[0][0] = __builtin_amdgcn_mfma_f32_16x16x32_bf16(afrag0, bf0_c, acc[0][0], 0, 0, 0);
        acc[1][0] = __builtin_amdgcn_mfma_f32_16x16x32_bf16(afrag1, bf0_c, acc[1][0], 0, 0, 0);
        acc[0][1] = __builtin_amdgcn_mfma_f32_16x16x32_bf16(afrag0, bf1_c, acc[0][1], 0, 0, 0);
        acc[1][1] = __builtin_amdgcn_mfma_f32_16x16x32_bf16(afrag1, bf1_c, acc[1][1], 0, 0, 0);
        acc[0][2] = __builtin_amdgcn_mfma_f32_16x16x32_bf16(afrag0, bf2_c, acc[0][2], 0, 0, 0);
        acc[1][2] = __builtin_amdgcn_mfma_f32_16x16x32_bf16(afrag1, bf2_c, acc[1][2], 0, 0, 0);
        acc[0][3] = __builtin_amdgcn_mfma_f32_16x16x32_bf16(afrag0, bf3_c, acc[0][3], 0, 0, 0);
        acc[1][3] = __builtin_amdgcn_mfma_f32_16x16x32_bf16(afrag1, bf3_c, acc[1][3], 0, 0, 0);

        // ---- rotate prefetch regs ----
        af0_c = af0_n; af1_c = af1_n;
        bf0_c = bf0_n; bf1_c = bf1_n; bf2_c = bf2_n; bf3_c = bf3_n;
    }

    // ---- epilogue: C/D layout col=lane&15, row=(lane>>4)*4+reg ----
    #pragma unroll
    for (int mt = 0; mt < 2; ++mt)
        #pragma unroll
        for (int cf = 0; cf < 4; ++cf)
            #pragma unroll
            for (int r = 0; r < 4; ++r) {
                const int gr = rowbase + mt * 16 + G * 4 + r;
                const int gc = colbase + cf * 16 + lr;
                out[(size_t)gr * 256 + gc] = acc[mt][cf][r];
            }
}

extern "C" void kernel_launch(void* const* d_in, const int* in_sizes, int n_in,
                              void* d_out, int out_size, void* d_ws, size_t ws_size,
                              hipStream_t stream) {
    const float* x     = (const float*)d_in[0];   // [8,4096,256]
    const float* theta = (const float*)d_in[1];   // [8]
    const float* W1    = (const float*)d_in[2];   // [1024,8]
    const float* W2    = (const float*)d_in[3];   // [256,1024]
    float* out = (float*)d_out;                   // [8,4096,256] f32

    const size_t need = (size_t)(256 * 1024 + W1ROWS * 8) * sizeof(unsigned short);
    const bool wsok = (ws_size >= need);

    if (wsok) {
        unsigned short* W2s = (unsigned short*)d_ws;   // 512KB granule-transposed bf16
        unsigned short* W1b = W2s + 256 * 1024;        // 1088x8 bf16 (pad rows zeroed)
        prep_kernel<<<129, 256, 0, stream>>>(W2, W1, W2s, W1b);
        ffq_kernel<true><<<1024, 256, 0, stream>>>(x, theta, nullptr, W1b, nullptr, W2s, out);
    } else {
        ffq_kernel<false><<<1024, 256, 0, stream>>>(x, theta, W1, nullptr, W2, nullptr, out);
    }
}

// Round 9
// 41.105 us; speedup vs baseline: 1.2508x; 1.1881x over previous
//
#include <hip/hip_runtime.h>
#include <hip/hip_bf16.h>

typedef __attribute__((ext_vector_type(8))) short  short8_t;
typedef __attribute__((ext_vector_type(4))) float  float4_t;
typedef __attribute__((ext_vector_type(4))) int    int4_t;
typedef __attribute__((ext_vector_type(2))) unsigned int uint2_t;

// f32 -> bf16 RNE (bit-twiddle; prepass/fallback only)
__device__ __forceinline__ unsigned short f2bf(float f) {
    unsigned int u = __builtin_bit_cast(unsigned int, f);
    u += 0x7FFFu + ((u >> 16) & 1u);
    return (unsigned short)(u >> 16);
}
__device__ __forceinline__ unsigned int cvtpk(float a, float b) {
    return (unsigned int)f2bf(a) | ((unsigned int)f2bf(b) << 16);
}
// HW packed convert (no builtin on gfx950)
__device__ __forceinline__ unsigned int cvtpk_hw(float a, float b) {
    unsigned int r;
    asm("v_cvt_pk_bf16_f32 %0, %1, %2" : "=v"(r) : "v"(a), "v"(b));
    return r;
}
// gfx950 cross-lane row swaps (dataflow-ordered)
__device__ __forceinline__ void plane32_swap(unsigned int& a, unsigned int& b) {
    asm("v_permlane32_swap_b32 %0, %1" : "+v"(a), "+v"(b));
}
__device__ __forceinline__ void plane16_swap(unsigned int& a, unsigned int& b) {
    asm("v_permlane16_swap_b32 %0, %1" : "+v"(a), "+v"(b));
}
// pinned 16B load the compiler cannot sink (T4 building block)
__device__ __forceinline__ void gld16(int4_t& d, const void* p) {
    asm volatile("global_load_dwordx4 %0, %1, off" : "=&v"(d) : "v"(p) : "memory");
}
// wait until only the just-issued 6 loads remain in flight; fence scheduling
__device__ __forceinline__ void wait_prev6() {
    asm volatile("s_waitcnt vmcnt(6)" ::: "memory");
    __builtin_amdgcn_sched_barrier(0);
}
// full drain: in-flight asm loads write VGPRs asynchronously; regalloc may reuse
// dead outputs' registers (epilogue addr math) -> must land everything first.
__device__ __forceinline__ void wait_all() {
    asm volatile("s_waitcnt vmcnt(0)" ::: "memory");
    __builtin_amdgcn_sched_barrier(0);
}

#define W1ROWS 1088   // 1024 + 64 zero-pad rows (unconditional a-frag loads)

// ---- prepass: W2 -> granule-transposed bf16 W2s[ks][e]; W1 -> bf16 W1b (+zero pad) ----
__global__ void prep_kernel(const float* __restrict__ W2, const float* __restrict__ W1,
                            unsigned short* __restrict__ W2s, unsigned short* __restrict__ W1b) {
    const int bid = blockIdx.x, tid = threadIdx.x;
    if (bid < 128) {
        const int idx = bid * 256 + tid;
        const int e   = idx >> 7;
        const int ks  = idx & 127;
        const float* src = W2 + (size_t)e * 1024 + ks * 8;
        const float4_t v0 = *reinterpret_cast<const float4_t*>(src);
        const float4_t v1 = *reinterpret_cast<const float4_t*>(src + 4);
        int4_t p;
        p[0] = (int)cvtpk(v0[0], v0[1]);
        p[1] = (int)cvtpk(v0[2], v0[3]);
        p[2] = (int)cvtpk(v1[0], v1[1]);
        p[3] = (int)cvtpk(v1[2], v1[3]);
        *reinterpret_cast<int4_t*>(W2s + ((size_t)ks * 256 + e) * 8) = p;
    } else {
        const int base = tid * 32;
        #pragma unroll
        for (int it = 0; it < 8; ++it) {
            const float4_t v = *reinterpret_cast<const float4_t*>(W1 + base + it * 4);
            uint2_t p;
            p[0] = cvtpk(v[0], v[1]);
            p[1] = cvtpk(v[2], v[3]);
            *reinterpret_cast<uint2_t*>(W1b + base + it * 4) = p;
        }
        if (tid < 16) {
            #pragma unroll
            for (int it = 0; it < 4; ++it) {
                int4_t z; z[0] = 0; z[1] = 0; z[2] = 0; z[3] = 0;
                *reinterpret_cast<int4_t*>(W1b + 8192 + tid * 32 + it * 8) = z;
            }
        }
    }
}

// ---- fused, zero-LDS, zero-barrier; asm-pinned 1-chunk-ahead register pipeline ----
template <bool WSOK>
__global__ __launch_bounds__(256, 4)
void ffq_kernel(const float* __restrict__ x,
                const float* __restrict__ theta,
                const float* __restrict__ W1f,
                const unsigned short* __restrict__ W1b,
                const float* __restrict__ W2f,
                const unsigned short* __restrict__ W2s,
                float* __restrict__ out)
{
    const int tid  = threadIdx.x;
    const int lane = tid & 63;
    const int w    = tid >> 6;
    const int bid  = blockIdx.x;
    const int ntile = bid & 3;
    const int mtile = (bid >> 2) * 4 + w;
    const int rowbase = mtile * 32;
    const int colbase = ntile * 64;
    const int lr = lane & 15;
    const int G  = lane >> 4;

    // ---- q B-frags (2 m-tiles of 16 rows): lane<16 holds q[row][k=0..7], rest zero ----
    short8_t qf0 = {0,0,0,0,0,0,0,0}, qf1 = {0,0,0,0,0,0,0,0};
    if (lane < 16) {
        float th[8];
        #pragma unroll
        for (int j = 0; j < 8; ++j) th[j] = theta[j];
        #pragma unroll
        for (int mt = 0; mt < 2; ++mt) {
            const float* xp = x + (size_t)(rowbase + mt * 16 + lane) * 256;
            const float4_t x0 = *reinterpret_cast<const float4_t*>(xp);
            const float4_t x1 = *reinterpret_cast<const float4_t*>(xp + 4);
            float qv[8];
            #pragma unroll
            for (int j = 0; j < 4; ++j) {
                qv[j]     = __cosf(x0[j]) * __cosf(th[j]);
                qv[4 + j] = __cosf(x1[j]) * __cosf(th[4 + j]);
            }
            int4_t pq;
            pq[0] = (int)cvtpk(qv[0], qv[1]);
            pq[1] = (int)cvtpk(qv[2], qv[3]);
            pq[2] = (int)cvtpk(qv[4], qv[5]);
            pq[3] = (int)cvtpk(qv[6], qv[7]);
            if (mt == 0) qf0 = __builtin_bit_cast(short8_t, pq);
            else         qf1 = __builtin_bit_cast(short8_t, pq);
        }
    }

    float4_t acc[2][4];
    #pragma unroll
    for (int i = 0; i < 2; ++i)
        #pragma unroll
        for (int j = 0; j < 4; ++j)
            acc[i][j] = (float4_t){0.f, 0.f, 0.f, 0.f};

    // h-phase + transpose + main-GEMM for one chunk, fragments as named regs
    auto compute = [&](const int4_t& a0, const int4_t& a1,
                       const int4_t& b0, const int4_t& b1,
                       const int4_t& b2, const int4_t& b3) {
        const short8_t af0 = __builtin_bit_cast(short8_t, a0);
        const short8_t af1 = __builtin_bit_cast(short8_t, a1);
        short8_t afrag0, afrag1;
        #pragma unroll
        for (int mt = 0; mt < 2; ++mt) {
            const short8_t qf = (mt == 0) ? qf0 : qf1;
            const float4_t t0 = __builtin_amdgcn_mfma_f32_16x16x32_bf16(
                af0, qf, (float4_t){0.f, 0.f, 0.f, 0.f}, 0, 0, 0);
            const float4_t t1 = __builtin_amdgcn_mfma_f32_16x16x32_bf16(
                af1, qf, (float4_t){0.f, 0.f, 0.f, 0.f}, 0, 0, 0);
            unsigned int A_ = cvtpk_hw(fmaxf(t0[0], 0.f), fmaxf(t0[1], 0.f));
            unsigned int B_ = cvtpk_hw(fmaxf(t0[2], 0.f), fmaxf(t0[3], 0.f));
            unsigned int C_ = cvtpk_hw(fmaxf(t1[0], 0.f), fmaxf(t1[1], 0.f));
            unsigned int D_ = cvtpk_hw(fmaxf(t1[2], 0.f), fmaxf(t1[3], 0.f));
            plane32_swap(A_, C_);
            plane16_swap(A_, C_);
            plane32_swap(B_, D_);
            plane16_swap(B_, D_);
            int4_t ua;
            ua[0] = (int)A_; ua[1] = (int)B_; ua[2] = (int)C_; ua[3] = (int)D_;
            if (mt == 0) afrag0 = __builtin_bit_cast(short8_t, ua);
            else         afrag1 = __builtin_bit_cast(short8_t, ua);
        }
        const short8_t bf0 = __builtin_bit_cast(short8_t, b0);
        const short8_t bf1 = __builtin_bit_cast(short8_t, b1);
        const short8_t bf2 = __builtin_bit_cast(short8_t, b2);
        const short8_t bf3 = __builtin_bit_cast(short8_t, b3);
        acc[0][0] = __builtin_amdgcn_mfma_f32_16x16x32_bf16(afrag0, bf0, acc[0][0], 0, 0, 0);
        acc[1][0] = __builtin_amdgcn_mfma_f32_16x16x32_bf16(afrag1, bf0, acc[1][0], 0, 0, 0);
        acc[0][1] = __builtin_amdgcn_mfma_f32_16x16x32_bf16(afrag0, bf1, acc[0][1], 0, 0, 0);
        acc[1][1] = __builtin_amdgcn_mfma_f32_16x16x32_bf16(afrag1, bf1, acc[1][1], 0, 0, 0);
        acc[0][2] = __builtin_amdgcn_mfma_f32_16x16x32_bf16(afrag0, bf2, acc[0][2], 0, 0, 0);
        acc[1][2] = __builtin_amdgcn_mfma_f32_16x16x32_bf16(afrag1, bf2, acc[1][2], 0, 0, 0);
        acc[0][3] = __builtin_amdgcn_mfma_f32_16x16x32_bf16(afrag0, bf3, acc[0][3], 0, 0, 0);
        acc[1][3] = __builtin_amdgcn_mfma_f32_16x16x32_bf16(afrag1, bf3, acc[1][3], 0, 0, 0);
    };

    if constexpr (WSOK) {
        auto a_addr = [&](int kc, int t) -> const void* {
            return (const void*)(W1b + (size_t)(kc + t * 16 + lane) * 8);
        };
        auto b_addr = [&](int kc, int cf) -> const void* {
            const int e = colbase + cf * 16 + lr;
            return (const void*)(W2s + (((size_t)(kc >> 3) + G) * 256 + e) * 8);
        };
        int4_t a0A, a1A, b0A, b1A, b2A, b3A;
        int4_t a0B, a1B, b0B, b1B, b2B, b3B;
        // prologue: chunk 0 into set A
        gld16(a0A, a_addr(0, 0)); gld16(a1A, a_addr(0, 1));
        gld16(b0A, b_addr(0, 0)); gld16(b1A, b_addr(0, 1));
        gld16(b2A, b_addr(0, 2)); gld16(b3A, b_addr(0, 3));

        #pragma unroll 1
        for (int kc = 0; kc < 1024; kc += 64) {
            const int k1 = kc + 32;
            const int k2 = (kc + 64) & 1023;   // wraps on last iter (drained before epilogue)
            // phase A: issue set B (chunk k1), wait set A, compute chunk kc
            gld16(a0B, a_addr(k1, 0)); gld16(a1B, a_addr(k1, 1));
            gld16(b0B, b_addr(k1, 0)); gld16(b1B, b_addr(k1, 1));
            gld16(b2B, b_addr(k1, 2)); gld16(b3B, b_addr(k1, 3));
            wait_prev6();
            compute(a0A, a1A, b0A, b1A, b2A, b3A);
            // phase B: issue set A (chunk k2), wait set B, compute chunk k1
            gld16(a0A, a_addr(k2, 0)); gld16(a1A, a_addr(k2, 1));
            gld16(b0A, b_addr(k2, 0)); gld16(b1A, b_addr(k2, 1));
            gld16(b2A, b_addr(k2, 2)); gld16(b3A, b_addr(k2, 3));
            wait_prev6();
            compute(a0B, a1B, b0B, b1B, b2B, b3B);
        }
        // CRITICAL: land the dangling wrap-around prefetch before regalloc can
        // reuse its dead output VGPRs in the epilogue (async clobber -> fault).
        wait_all();
    } else {
        // fallback (no workspace): simple compiler-scheduled loop, correctness-first
        for (int kc = 0; kc < 1024; kc += 32) {
            int4_t a0 = {0,0,0,0}, a1 = {0,0,0,0};
            if (lane < 16) {
                #pragma unroll
                for (int t = 0; t < 2; ++t) {
                    const float* src = W1f + (size_t)(kc + t * 16 + lane) * 8;
                    const float4_t v0 = *reinterpret_cast<const float4_t*>(src);
                    const float4_t v1 = *reinterpret_cast<const float4_t*>(src + 4);
                    int4_t p;
                    p[0] = (int)cvtpk(v0[0], v0[1]);
                    p[1] = (int)cvtpk(v0[2], v0[3]);
                    p[2] = (int)cvtpk(v1[0], v1[1]);
                    p[3] = (int)cvtpk(v1[2], v1[3]);
                    if (t == 0) a0 = p; else a1 = p;
                }
            }
            int4_t b[4];
            #pragma unroll
            for (int cf = 0; cf < 4; ++cf) {
                const int e = colbase + cf * 16 + lr;
                const float* p = W2f + (size_t)e * 1024 + kc + G * 8;
                const float4_t v0 = *reinterpret_cast<const float4_t*>(p);
                const float4_t v1 = *reinterpret_cast<const float4_t*>(p + 4);
                int4_t pb;
                pb[0] = (int)cvtpk(v0[0], v0[1]);
                pb[1] = (int)cvtpk(v0[2], v0[3]);
                pb[2] = (int)cvtpk(v1[0], v1[1]);
                pb[3] = (int)cvtpk(v1[2], v1[3]);
                b[cf] = pb;
            }
            compute(a0, a1, b[0], b[1], b[2], b[3]);
        }
    }

    // ---- epilogue: C/D layout col=lane&15, row=(lane>>4)*4+reg ----
    #pragma unroll
    for (int mt = 0; mt < 2; ++mt)
        #pragma unroll
        for (int cf = 0; cf < 4; ++cf)
            #pragma unroll
            for (int r = 0; r < 4; ++r) {
                const int gr = rowbase + mt * 16 + G * 4 + r;
                const int gc = colbase + cf * 16 + lr;
                out[(size_t)gr * 256 + gc] = acc[mt][cf][r];
            }
}

extern "C" void kernel_launch(void* const* d_in, const int* in_sizes, int n_in,
                              void* d_out, int out_size, void* d_ws, size_t ws_size,
                              hipStream_t stream) {
    const float* x     = (const float*)d_in[0];   // [8,4096,256]
    const float* theta = (const float*)d_in[1];   // [8]
    const float* W1    = (const float*)d_in[2];   // [1024,8]
    const float* W2    = (const float*)d_in[3];   // [256,1024]
    float* out = (float*)d_out;                   // [8,4096,256] f32

    const size_t need = (size_t)(256 * 1024 + W1ROWS * 8) * sizeof(unsigned short);
    const bool wsok = (ws_size >= need);

    if (wsok) {
        unsigned short* W2s = (unsigned short*)d_ws;   // 512KB granule-transposed bf16
        unsigned short* W1b = W2s + 256 * 1024;        // 1088x8 bf16 (pad rows zeroed)
        prep_kernel<<<129, 256, 0, stream>>>(W2, W1, W2s, W1b);
        ffq_kernel<true><<<1024, 256, 0, stream>>>(x, theta, nullptr, W1b, nullptr, W2s, out);
    } else {
        ffq_kernel<false><<<1024, 256, 0, stream>>>(x, theta, W1, nullptr, W2, nullptr, out);
    }
}

// Round 10
// 40.748 us; speedup vs baseline: 1.2617x; 1.0088x over previous
//
#include <hip/hip_runtime.h>
#include <hip/hip_bf16.h>

typedef __attribute__((ext_vector_type(8))) short  short8_t;
typedef __attribute__((ext_vector_type(4))) float  float4_t;
typedef __attribute__((ext_vector_type(4))) int    int4_t;
typedef __attribute__((ext_vector_type(2))) unsigned int uint2_t;

// f32 -> bf16 RNE (bit-twiddle; prepass/fallback only)
__device__ __forceinline__ unsigned short f2bf(float f) {
    unsigned int u = __builtin_bit_cast(unsigned int, f);
    u += 0x7FFFu + ((u >> 16) & 1u);
    return (unsigned short)(u >> 16);
}
__device__ __forceinline__ unsigned int cvtpk(float a, float b) {
    return (unsigned int)f2bf(a) | ((unsigned int)f2bf(b) << 16);
}
// HW packed convert (no builtin on gfx950)
__device__ __forceinline__ unsigned int cvtpk_hw(float a, float b) {
    unsigned int r;
    asm("v_cvt_pk_bf16_f32 %0, %1, %2" : "=v"(r) : "v"(a), "v"(b));
    return r;
}
// gfx950 cross-lane row swaps (dataflow-ordered)
__device__ __forceinline__ void plane32_swap(unsigned int& a, unsigned int& b) {
    asm("v_permlane32_swap_b32 %0, %1" : "+v"(a), "+v"(b));
}
__device__ __forceinline__ void plane16_swap(unsigned int& a, unsigned int& b) {
    asm("v_permlane16_swap_b32 %0, %1" : "+v"(a), "+v"(b));
}
// pinned 16B load the compiler cannot sink (T4 building block)
__device__ __forceinline__ void gld16(int4_t& d, const void* p) {
    asm volatile("global_load_dwordx4 %0, %1, off" : "=&v"(d) : "v"(p) : "memory");
}
// 2-deep pipeline wait: the 2 younger sets (12 loads) stay in flight
__device__ __forceinline__ void wait12() {
    asm volatile("s_waitcnt vmcnt(12)" ::: "memory");
    __builtin_amdgcn_sched_barrier(0);
}
// full drain before epilogue: in-flight asm loads write VGPRs asynchronously;
// regalloc may reuse dead outputs' registers -> must land everything first.
__device__ __forceinline__ void wait_all() {
    asm volatile("s_waitcnt vmcnt(0)" ::: "memory");
    __builtin_amdgcn_sched_barrier(0);
}

#define W1ROWS 1088   // 1024 + 64 zero-pad rows (covers wrap reads kc+16+lane <= 1071)

// ---- prepass: W2 -> granule-transposed bf16 W2s[ks][e]; W1 -> bf16 W1b (+zero pad) ----
__global__ void prep_kernel(const float* __restrict__ W2, const float* __restrict__ W1,
                            unsigned short* __restrict__ W2s, unsigned short* __restrict__ W1b) {
    const int bid = blockIdx.x, tid = threadIdx.x;
    if (bid < 128) {
        const int idx = bid * 256 + tid;
        const int e   = idx >> 7;
        const int ks  = idx & 127;
        const float* src = W2 + (size_t)e * 1024 + ks * 8;
        const float4_t v0 = *reinterpret_cast<const float4_t*>(src);
        const float4_t v1 = *reinterpret_cast<const float4_t*>(src + 4);
        int4_t p;
        p[0] = (int)cvtpk(v0[0], v0[1]);
        p[1] = (int)cvtpk(v0[2], v0[3]);
        p[2] = (int)cvtpk(v1[0], v1[1]);
        p[3] = (int)cvtpk(v1[2], v1[3]);
        *reinterpret_cast<int4_t*>(W2s + ((size_t)ks * 256 + e) * 8) = p;
    } else {
        const int base = tid * 32;
        #pragma unroll
        for (int it = 0; it < 8; ++it) {
            const float4_t v = *reinterpret_cast<const float4_t*>(W1 + base + it * 4);
            uint2_t p;
            p[0] = cvtpk(v[0], v[1]);
            p[1] = cvtpk(v[2], v[3]);
            *reinterpret_cast<uint2_t*>(W1b + base + it * 4) = p;
        }
        if (tid < 16) {
            #pragma unroll
            for (int it = 0; it < 4; ++it) {
                int4_t z; z[0] = 0; z[1] = 0; z[2] = 0; z[3] = 0;
                *reinterpret_cast<int4_t*>(W1b + 8192 + tid * 32 + it * 8) = z;
            }
        }
    }
}

// ---- fused, zero-LDS, zero-barrier; 64x64 wave tiles; 2-deep asm-pinned pipeline ----
// 2048 waves; block = 4 waves on one 256-row stripe, shared colbase (B addrs identical
// across waves -> L1-hot). Per-wave fragment traffic halved vs 32x64 tiles.
template <bool WSOK>
__global__ __launch_bounds__(256, 2)
void ffq_kernel(const float* __restrict__ x,
                const float* __restrict__ theta,
                const float* __restrict__ W1f,
                const unsigned short* __restrict__ W1b,
                const float* __restrict__ W2f,
                const unsigned short* __restrict__ W2s,
                float* __restrict__ out)
{
    const int tid  = threadIdx.x;
    const int lane = tid & 63;
    const int w    = tid >> 6;
    const int bid  = blockIdx.x;
    const int ntile   = bid & 3;                    // 4 col-tiles of 64
    const int rowbase = (bid >> 2) * 256 + w * 64;  // 128 row-blocks of 256
    const int colbase = ntile * 64;
    const int lr = lane & 15;
    const int G  = lane >> 4;

    // ---- q B-frags (4 m-tiles of 16 rows): lane<16 holds q[row][k=0..7], rest zero ----
    short8_t qf[4];
    #pragma unroll
    for (int mt = 0; mt < 4; ++mt) {
        short8_t v = {0,0,0,0,0,0,0,0};
        if (lane < 16) {
            const float* xp = x + (size_t)(rowbase + mt * 16 + lane) * 256;
            const float4_t x0 = *reinterpret_cast<const float4_t*>(xp);
            const float4_t x1 = *reinterpret_cast<const float4_t*>(xp + 4);
            float qv[8];
            #pragma unroll
            for (int j = 0; j < 4; ++j) {
                qv[j]     = __cosf(x0[j]) * __cosf(theta[j]);
                qv[4 + j] = __cosf(x1[j]) * __cosf(theta[4 + j]);
            }
            int4_t pq;
            pq[0] = (int)cvtpk(qv[0], qv[1]);
            pq[1] = (int)cvtpk(qv[2], qv[3]);
            pq[2] = (int)cvtpk(qv[4], qv[5]);
            pq[3] = (int)cvtpk(qv[6], qv[7]);
            v = __builtin_bit_cast(short8_t, pq);
        }
        qf[mt] = v;
    }

    float4_t acc[4][4];
    #pragma unroll
    for (int i = 0; i < 4; ++i)
        #pragma unroll
        for (int j = 0; j < 4; ++j)
            acc[i][j] = (float4_t){0.f, 0.f, 0.f, 0.f};

    // h-phase + in-register transpose + main GEMM for one 32-K chunk
    auto compute = [&](const int4_t& a0, const int4_t& a1,
                       const int4_t& b0, const int4_t& b1,
                       const int4_t& b2, const int4_t& b3) {
        const short8_t af0 = __builtin_bit_cast(short8_t, a0);
        const short8_t af1 = __builtin_bit_cast(short8_t, a1);
        short8_t afrag[4];
        #pragma unroll
        for (int mt = 0; mt < 4; ++mt) {
            const float4_t t0 = __builtin_amdgcn_mfma_f32_16x16x32_bf16(
                af0, qf[mt], (float4_t){0.f, 0.f, 0.f, 0.f}, 0, 0, 0);
            const float4_t t1 = __builtin_amdgcn_mfma_f32_16x16x32_bf16(
                af1, qf[mt], (float4_t){0.f, 0.f, 0.f, 0.f}, 0, 0, 0);
            unsigned int A_ = cvtpk_hw(fmaxf(t0[0], 0.f), fmaxf(t0[1], 0.f));
            unsigned int B_ = cvtpk_hw(fmaxf(t0[2], 0.f), fmaxf(t0[3], 0.f));
            unsigned int C_ = cvtpk_hw(fmaxf(t1[0], 0.f), fmaxf(t1[1], 0.f));
            unsigned int D_ = cvtpk_hw(fmaxf(t1[2], 0.f), fmaxf(t1[3], 0.f));
            plane32_swap(A_, C_);
            plane16_swap(A_, C_);
            plane32_swap(B_, D_);
            plane16_swap(B_, D_);
            int4_t ua;
            ua[0] = (int)A_; ua[1] = (int)B_; ua[2] = (int)C_; ua[3] = (int)D_;
            afrag[mt] = __builtin_bit_cast(short8_t, ua);
        }
        const short8_t bfr[4] = {
            __builtin_bit_cast(short8_t, b0), __builtin_bit_cast(short8_t, b1),
            __builtin_bit_cast(short8_t, b2), __builtin_bit_cast(short8_t, b3) };
        #pragma unroll
        for (int mt = 0; mt < 4; ++mt)
            #pragma unroll
            for (int cf = 0; cf < 4; ++cf)
                acc[mt][cf] = __builtin_amdgcn_mfma_f32_16x16x32_bf16(
                    afrag[mt], bfr[cf], acc[mt][cf], 0, 0, 0);
    };

    if constexpr (WSOK) {
        auto a_addr = [&](int kc, int t) -> const void* {
            return (const void*)(W1b + (size_t)(kc + t * 16 + lane) * 8);
        };
        auto b_addr = [&](int kc, int cf) -> const void* {
            const int e = colbase + cf * 16 + lr;
            return (const void*)(W2s + (((size_t)(kc >> 3) + G) * 256 + e) * 8);
        };
        // 4 named fragment sets, 2-chunk-ahead pipeline
        int4_t Aa0, Aa1, Ab0, Ab1, Ab2, Ab3;
        int4_t Ba0, Ba1, Bb0, Bb1, Bb2, Bb3;
        int4_t Ca0, Ca1, Cb0, Cb1, Cb2, Cb3;
        int4_t Da0, Da1, Db0, Db1, Db2, Db3;

        #define ISSUE(P, K) do { const int kk_ = (K) & 1023;              \
            gld16(P##a0, a_addr(kk_, 0)); gld16(P##a1, a_addr(kk_, 1));   \
            gld16(P##b0, b_addr(kk_, 0)); gld16(P##b1, b_addr(kk_, 1));   \
            gld16(P##b2, b_addr(kk_, 2)); gld16(P##b3, b_addr(kk_, 3)); } while (0)
        #define COMPUTE(P) compute(P##a0, P##a1, P##b0, P##b1, P##b2, P##b3)

        ISSUE(A, 0);
        ISSUE(B, 32);
        #pragma unroll 1
        for (int kc = 0; kc < 1024; kc += 128) {
            ISSUE(C, kc + 64);  wait12(); COMPUTE(A);
            ISSUE(D, kc + 96);  wait12(); COMPUTE(B);
            ISSUE(A, kc + 128); wait12(); COMPUTE(C);   // wraps on last iter
            ISSUE(B, kc + 160); wait12(); COMPUTE(D);   // wraps on last iter
        }
        // land dangling wrap-around prefetches before regalloc reuses their regs
        wait_all();
        #undef ISSUE
        #undef COMPUTE
    } else {
        // fallback (no workspace): simple compiler-scheduled loop, correctness-first
        for (int kc = 0; kc < 1024; kc += 32) {
            int4_t a0 = {0,0,0,0}, a1 = {0,0,0,0};
            if (lane < 16) {
                #pragma unroll
                for (int t = 0; t < 2; ++t) {
                    const float* src = W1f + (size_t)(kc + t * 16 + lane) * 8;
                    const float4_t v0 = *reinterpret_cast<const float4_t*>(src);
                    const float4_t v1 = *reinterpret_cast<const float4_t*>(src + 4);
                    int4_t p;
                    p[0] = (int)cvtpk(v0[0], v0[1]);
                    p[1] = (int)cvtpk(v0[2], v0[3]);
                    p[2] = (int)cvtpk(v1[0], v1[1]);
                    p[3] = (int)cvtpk(v1[2], v1[3]);
                    if (t == 0) a0 = p; else a1 = p;
                }
            }
            int4_t b[4];
            #pragma unroll
            for (int cf = 0; cf < 4; ++cf) {
                const int e = colbase + cf * 16 + lr;
                const float* p = W2f + (size_t)e * 1024 + kc + G * 8;
                const float4_t v0 = *reinterpret_cast<const float4_t*>(p);
                const float4_t v1 = *reinterpret_cast<const float4_t*>(p + 4);
                int4_t pb;
                pb[0] = (int)cvtpk(v0[0], v0[1]);
                pb[1] = (int)cvtpk(v0[2], v0[3]);
                pb[2] = (int)cvtpk(v1[0], v1[1]);
                pb[3] = (int)cvtpk(v1[2], v1[3]);
                b[cf] = pb;
            }
            compute(a0, a1, b[0], b[1], b[2], b[3]);
        }
    }

    // ---- epilogue: C/D layout col=lane&15, row=(lane>>4)*4+reg ----
    #pragma unroll
    for (int mt = 0; mt < 4; ++mt)
        #pragma unroll
        for (int cf = 0; cf < 4; ++cf)
            #pragma unroll
            for (int r = 0; r < 4; ++r) {
                const int gr = rowbase + mt * 16 + G * 4 + r;
                const int gc = colbase + cf * 16 + lr;
                out[(size_t)gr * 256 + gc] = acc[mt][cf][r];
            }
}

extern "C" void kernel_launch(void* const* d_in, const int* in_sizes, int n_in,
                              void* d_out, int out_size, void* d_ws, size_t ws_size,
                              hipStream_t stream) {
    const float* x     = (const float*)d_in[0];   // [8,4096,256]
    const float* theta = (const float*)d_in[1];   // [8]
    const float* W1    = (const float*)d_in[2];   // [1024,8]
    const float* W2    = (const float*)d_in[3];   // [256,1024]
    float* out = (float*)d_out;                   // [8,4096,256] f32

    const size_t need = (size_t)(256 * 1024 + W1ROWS * 8) * sizeof(unsigned short);
    const bool wsok = (ws_size >= need);

    if (wsok) {
        unsigned short* W2s = (unsigned short*)d_ws;   // 512KB granule-transposed bf16
        unsigned short* W1b = W2s + 256 * 1024;        // 1088x8 bf16 (pad rows zeroed)
        prep_kernel<<<129, 256, 0, stream>>>(W2, W1, W2s, W1b);
        ffq_kernel<true><<<512, 256, 0, stream>>>(x, theta, nullptr, W1b, nullptr, W2s, out);
    } else {
        ffq_kernel<false><<<512, 256, 0, stream>>>(x, theta, W1, nullptr, W2, nullptr, out);
    }
}